// Round 8
// baseline (41.880 us; speedup 1.0000x reference)
//
#include <hip/hip_runtime.h>

#define TPB   256    // nn threads per block (4 waves)
#define QPT   8      // query points per thread (registers)
#define SPLIT 64     // database slices per direction (4096/64 = 64 = one stage)
#define RTPB  256    // reduce threads per block
#define QCHUNK 64    // queries per reduce block
#define MAXPART 1024 // max partials the fused final combine supports

// ---------------------------------------------------------------------------
// nn: directed nearest-neighbor min, both directions in one launch.
//   blockIdx.z = 0 : query = pred  (NA=N), DB = target (NB=M), all valid
//   blockIdx.z = 1 : query = target(NA=M), DB = pred   (NB=N), label-masked
// Staging packs each DB point as (-2x,-2y,-2z,|t|^2) (label poisoning folded
// in: invalid -> coords 0, tn = 1e10 == reference BIG). Candidate is a pure
// 3-fma chain; min over it equals min over d shifted by |p|^2 (added once per
// query at the end, clamped >= 0).
// QPT=8, SPLIT=64, natiles=2: grid = (B*2, 64, 2) = 1024 blocks (4/CU,
// 16 waves/CU); each query loaded by 64 blocks (was 128); one 64-point stage,
// one barrier; minsplit = 8.4 MB (was 16.8).
// Each (dir,b,at,split) block writes a private minsplit row slice: no atomics
// in the hot path, bit-deterministic. Block (0,0,0) resets the reduce
// counter (visible at next dispatch boundary).
// ---------------------------------------------------------------------------
__global__ void __launch_bounds__(TPB) nn_kernel(
    const float* __restrict__ pred,
    const float* __restrict__ target,
    const int*   __restrict__ label,
    float* __restrict__ minsplit,     // [2][B][SPLIT][stride]
    unsigned int* __restrict__ counter,
    int B, int N, int M, int natmax, int stride)
{
    __shared__ float4 tile[TPB];

    if (blockIdx.x == 0 && blockIdx.y == 0 && blockIdx.z == 0 && threadIdx.x == 0) {
        *counter = 0u;
    }

    const int dir = blockIdx.z;
    const float* __restrict__ A  = dir ? target : pred;
    const float* __restrict__ Bp = dir ? pred   : target;
    const int NA = dir ? M : N;
    const int NB = dir ? N : M;
    const int* __restrict__ labB = dir ? label : nullptr;

    const int natiles = (NA + TPB * QPT - 1) / (TPB * QPT);
    const int b  = blockIdx.x / natmax;
    const int at = blockIdx.x - b * natmax;
    if (at >= natiles) return;

    const size_t abase = (size_t)b * NA;

    float px[QPT], py[QPT], pz[QPT], pn[QPT], best[QPT];
#pragma unroll
    for (int q = 0; q < QPT; ++q) {
        int a = at * (TPB * QPT) + q * TPB + threadIdx.x;
        int idx = (a < NA) ? a : 0;
        const float* sp = A + (abase + idx) * 3;
        px[q] = sp[0];
        py[q] = sp[1];
        pz[q] = sp[2];
        pn[q] = fmaf(px[q], px[q], fmaf(py[q], py[q], pz[q] * pz[q]));
        best[q] = 3.0e38f;
    }

    const int slen = (NB + SPLIT - 1) / SPLIT;
    const int sbeg = blockIdx.y * slen;
    const int send = min(sbeg + slen, NB);
    const size_t bbase = (size_t)b * NB;

    for (int c = sbeg; c < send; c += TPB) {
        const int cnt = min(send - c, TPB);
        if (threadIdx.x < cnt) {
            int m = c + threadIdx.x;
            const float* sp = Bp + (bbase + m) * 3;
            float x = sp[0], y = sp[1], z = sp[2];
            float tn = fmaf(x, x, fmaf(y, y, z * z));
            if (labB != nullptr && labB[bbase + m] != 1) {   // invalid point
                x = 0.0f; y = 0.0f; z = 0.0f; tn = 1.0e10f;
            }
            tile[threadIdx.x] = make_float4(-2.f * x, -2.f * y, -2.f * z, tn);
        }
        __syncthreads();

        const int jeven = cnt & ~1;
#pragma unroll 4
        for (int j = 0; j < jeven; j += 2) {
            float4 t0 = tile[j];      // wave-uniform -> LDS broadcast
            float4 t1 = tile[j + 1];
#pragma unroll
            for (int q = 0; q < QPT; ++q) {
                float v0 = fmaf(px[q], t0.x, fmaf(py[q], t0.y, fmaf(pz[q], t0.z, t0.w)));
                float v1 = fmaf(px[q], t1.x, fmaf(py[q], t1.y, fmaf(pz[q], t1.z, t1.w)));
                best[q] = fminf(best[q], fminf(v0, v1));   // -> v_min3_f32
            }
        }
        if (cnt & 1) {
            float4 t0 = tile[cnt - 1];
#pragma unroll
            for (int q = 0; q < QPT; ++q) {
                float v0 = fmaf(px[q], t0.x, fmaf(py[q], t0.y, fmaf(pz[q], t0.z, t0.w)));
                best[q] = fminf(best[q], v0);
            }
        }
        __syncthreads();              // protect tile before next stage write
    }

    float* out = minsplit + (((size_t)dir * B + b) * SPLIT + blockIdx.y) * stride;
#pragma unroll
    for (int q = 0; q < QPT; ++q) {
        int a = at * (TPB * QPT) + q * TPB + threadIdx.x;
        if (a < NA) {
            out[a] = fmaxf(best[q] + pn[q], 0.0f);
        }
    }
}

// ---------------------------------------------------------------------------
// reduce: one block per (dir, b, 64-query chunk) = 512 blocks. 256 threads =
// 64 queries x 4 slice-groups; coalesced (256 B/wave/slice) strided min-
// reduce over 64 slices, LDS combine, sqrt + masked sums, wave shuffle ->
// one partial pair per block (atomicExch, device-scope). Last block (counter)
// loads all partials in parallel (atomic reads) and does the fixed-order
// final combine. Deterministic regardless of arrival order.
// ---------------------------------------------------------------------------
__global__ void __launch_bounds__(RTPB) reduce_kernel(
    const float* __restrict__ minsplit,
    const int* __restrict__ label,
    float* __restrict__ pS, float* __restrict__ pC,
    unsigned int* __restrict__ counter,
    float* __restrict__ out,
    int B, int N, int M, int chunksN, int chunksM, int stride, int nblocks)
{
    __shared__ float red[RTPB];
    const int r = blockIdx.x;

    int dir, b, ch, NA;
    if (r < B * chunksN) { dir = 0; b = r / chunksN; ch = r - b * chunksN; NA = N; }
    else { int r2 = r - B * chunksN; dir = 1; b = r2 / chunksM; ch = r2 - b * chunksM; NA = M; }

    const int lane = threadIdx.x & 63;
    const int sg   = threadIdx.x >> 6;           // slice group 0..3
    const int q    = ch * QCHUNK + lane;

    const float* base = minsplit + ((size_t)(dir * B + b) * SPLIT) * stride + q;

    float m = 3.0e38f;
    if (q < NA) {
#pragma unroll 8
        for (int sp = sg; sp < SPLIT; sp += 4) {
            m = fminf(m, base[(size_t)sp * stride]);
        }
    }
    red[threadIdx.x] = m;
    __syncthreads();

    float s = 0.0f, cc = 0.0f;
    if (threadIdx.x < QCHUNK) {
        float mm = fminf(fminf(red[lane], red[64 + lane]),
                         fminf(red[128 + lane], red[192 + lane]));
        if (q < NA) {
            if (dir == 0) {
                if (label[(size_t)b * N + q] == 1) { s = sqrtf(mm); cc = 1.0f; }
            } else {
                s = sqrtf(mm);
            }
        }
        for (int off = 32; off > 0; off >>= 1) {   // fixed-order wave reduce
            s  += __shfl_down(s, off);
            cc += __shfl_down(cc, off);
        }
    }

    __shared__ unsigned int is_last;
    if (threadIdx.x == 0) {
        atomicExch(&pS[r], s);                 // device-scope, XCD-coherent
        atomicExch(&pC[r], cc);
        __threadfence();
        unsigned int old = atomicAdd(counter, 1u);
        is_last = (old == (unsigned int)(nblocks - 1)) ? 1u : 0u;
    }
    __syncthreads();

    if (is_last) {
        __shared__ float sS[MAXPART], sC[MAXPART];
        for (int i = threadIdx.x; i < nblocks; i += RTPB) {
            sS[i] = atomicAdd(&pS[i], 0.0f);   // device-scope reads, parallel
            sC[i] = atomicAdd(&pC[i], 0.0f);
        }
        __syncthreads();
        if (threadIdx.x == 0) {
            float acc = 0.0f;
            for (int bb = 0; bb < B; ++bb) {
                float S1 = 0.0f, C1 = 0.0f, S2 = 0.0f;
                for (int i = 0; i < chunksN; ++i) {
                    S1 += sS[bb * chunksN + i];
                    C1 += sC[bb * chunksN + i];
                }
                for (int i = 0; i < chunksM; ++i) {
                    S2 += sS[B * chunksN + bb * chunksM + i];
                }
                float m1 = S1 / fmaxf(C1, 1.0f);
                float m2 = S2 / (float)M;
                acc += 0.5f * (m1 + m2);
            }
            out[0] = acc / (float)B;   // * LOSS_WEIGHT (== 1.0)
        }
    }
}

// ---------------------------------------------------------------------------
extern "C" void kernel_launch(void* const* d_in, const int* in_sizes, int n_in,
                              void* d_out, int out_size, void* d_ws, size_t ws_size,
                              hipStream_t stream) {
    const float* pred   = (const float*)d_in[0];  // B*N*3 f32
    const float* target = (const float*)d_in[1];  // B*M*3 f32
    const int*   label  = (const int*)  d_in[2];  // B*N   i32

    const int B = in_sizes[3];                 // nums has shape (B,)
    const int N = in_sizes[2] / B;             // label is B*N
    const int M = in_sizes[1] / (3 * B);       // target is B*M*3

    const int stride = (N > M) ? N : M;

    // workspace layout (~8.5 MiB of the provided scratch)
    float* minsplit = (float*)d_ws;                               // 2*B*SPLIT*stride
    const int chunksN = (N + QCHUNK - 1) / QCHUNK;
    const int chunksM = (M + QCHUNK - 1) / QCHUNK;
    const int nred = B * (chunksN + chunksM);
    float* pS = minsplit + (size_t)2 * B * SPLIT * stride;        // nred
    float* pC = pS + nred;                                        // nred
    unsigned int* counter = (unsigned int*)(pC + nred);

    const int nat1 = (N + TPB * QPT - 1) / (TPB * QPT);
    const int nat2 = (M + TPB * QPT - 1) / (TPB * QPT);
    const int natmax = (nat1 > nat2) ? nat1 : nat2;
    dim3 g(B * natmax, SPLIT, 2);
    nn_kernel<<<g, TPB, 0, stream>>>(pred, target, label, minsplit, counter,
                                     B, N, M, natmax, stride);

    reduce_kernel<<<nred, RTPB, 0, stream>>>(minsplit, label, pS, pC, counter,
                                             (float*)d_out,
                                             B, N, M, chunksN, chunksM, stride, nred);
}